// Round 1
// baseline (457.163 us; speedup 1.0000x reference)
//
#include <hip/hip_runtime.h>
#include <hip/hip_bf16.h>

#define SLEN  256
#define BSZ   8
#define NHEAD 16
#define DHEAD 64
#define INDIM 1024
#define LN_EPS 1e-5f

typedef __attribute__((ext_vector_type(4))) float f32x4;
typedef __attribute__((ext_vector_type(8))) short bf16x8;

__device__ inline unsigned short f2bf(float x) {
  __hip_bfloat16 b = __float2bfloat16(x);
  union { __hip_bfloat16 b; unsigned short u; } cv;
  cv.b = b;
  return cv.u;
}

// --------------------------------------------------------------------------
// Kernel 1: convert out_w (1024x1024 fp32) -> bf16
// --------------------------------------------------------------------------
__global__ void conv_bf16_k(const float* __restrict__ src,
                            unsigned short* __restrict__ dst) {
  int i = (blockIdx.x * 256 + threadIdx.x) * 4;
  float4 v = *(const float4*)(src + i);
  ushort4 o;
  o.x = f2bf(v.x);
  o.y = f2bf(v.y);
  o.z = f2bf(v.z);
  o.w = f2bf(v.w);
  *(ushort4*)(dst + i) = o;
}

// --------------------------------------------------------------------------
// Kernel 2: per-row LayerNorm stats of h: mu, rsigma  (2048 rows x 1024)
// --------------------------------------------------------------------------
__global__ void row_stats_k(const float* __restrict__ h,
                            float* __restrict__ stats) {
  int r = blockIdx.x;             // 0..2047
  int tid = threadIdx.x;          // 256 threads
  const float* row = h + (size_t)r * INDIM;
  float4 v = *(const float4*)(row + tid * 4);
  float s  = v.x + v.y + v.z + v.w;
  float s2 = v.x * v.x + v.y * v.y + v.z * v.z + v.w * v.w;
  #pragma unroll
  for (int m = 32; m >= 1; m >>= 1) {
    s  += __shfl_xor(s, m);
    s2 += __shfl_xor(s2, m);
  }
  __shared__ float ls[4], ls2[4];
  int wave = tid >> 6;
  if ((tid & 63) == 0) { ls[wave] = s; ls2[wave] = s2; }
  __syncthreads();
  if (tid == 0) {
    float S  = ls[0] + ls[1] + ls[2] + ls[3];
    float S2 = ls2[0] + ls2[1] + ls2[2] + ls2[3];
    float mu = S * (1.0f / INDIM);
    float var = S2 * (1.0f / INDIM) - mu * mu;
    stats[2 * r]     = mu;
    stats[2 * r + 1] = rsqrtf(var + LN_EPS);
  }
}

// --------------------------------------------------------------------------
// Kernel 3: SRWM sequential scan. 128 blocks (one per (b,head) chain),
// 256 threads = 4 waves:
//   wave 0: owns Wy rows (lane=row), emits y (bf16) per step
//   wave 1: owns Wq, computes q = softmax(Wq x)
//   wave 2: owns Wk, computes k = softmax(Wk x)
//   wave 3: owns wb (64x4), computes beta, stages x_t into LDS
// --------------------------------------------------------------------------
__global__ __launch_bounds__(256, 1) void srwm_scan_k(
    const float* __restrict__ h,
    const float* __restrict__ Wy0,
    const float* __restrict__ Wq0,
    const float* __restrict__ Wk0,
    const float* __restrict__ wb0,
    unsigned short* __restrict__ ys_bf) {
  const int chain = blockIdx.x;         // 0..127
  const int b    = chain >> 4;
  const int head = chain & 15;
  const int tid  = threadIdx.x;
  const int wave = tid >> 6;
  const int lane = tid & 63;

  __shared__ __align__(16) float xbuf[64];
  __shared__ __align__(16) float qbuf[64];
  __shared__ __align__(16) float kbuf[64];
  __shared__ float betabuf[4];

  const float* xbase = h + (size_t)b * INDIM + head * DHEAD;

  if (wave < 3) {
    const float* Wsel = (wave == 0) ? Wy0 : ((wave == 1) ? Wq0 : Wk0);
    const float* wrow = Wsel + (size_t)head * DHEAD * DHEAD + (size_t)lane * DHEAD;
    float w[64];
    #pragma unroll
    for (int j = 0; j < 64; j += 4) {
      float4 t4 = *(const float4*)(wrow + j);
      w[j] = t4.x; w[j + 1] = t4.y; w[j + 2] = t4.z; w[j + 3] = t4.w;
    }
    __syncthreads();  // prologue: x_0 staged by wave 3
    for (int t = 0; t < SLEN; ++t) {
      // ---- region B: matvec1 with x_t (LDS broadcast reads) ----
      float a0 = 0.f, a1 = 0.f, a2 = 0.f, a3 = 0.f;
      #pragma unroll
      for (int j = 0; j < 64; j += 4) {
        float4 x4 = *(const float4*)(xbuf + j);
        a0 += w[j]     * x4.x;
        a1 += w[j + 1] * x4.y;
        a2 += w[j + 2] * x4.z;
        a3 += w[j + 3] * x4.w;
      }
      float v = (a0 + a1) + (a2 + a3);
      float yout = v;
      if (wave != 0) {
        // wave-local softmax across the 64 rows this wave owns
        float m = v;
        #pragma unroll
        for (int s = 32; s >= 1; s >>= 1) m = fmaxf(m, __shfl_xor(m, s));
        float e = __expf(v - m);
        float ssum = e;
        #pragma unroll
        for (int s = 32; s >= 1; s >>= 1) ssum += __shfl_xor(ssum, s);
        float sm = e / ssum;
        float* obuf = (wave == 1) ? qbuf : kbuf;
        obuf[lane] = sm;
      }
      __syncthreads();  // alpha: q,k,beta visible
      // ---- region C: dv = W (q-k); W += beta*dv*k^T ----
      float kreg[64];
      float d0 = 0.f, d1 = 0.f, d2 = 0.f, d3 = 0.f;
      #pragma unroll
      for (int j = 0; j < 64; j += 4) {
        float4 q4 = *(const float4*)(qbuf + j);
        float4 k4 = *(const float4*)(kbuf + j);
        kreg[j] = k4.x; kreg[j + 1] = k4.y; kreg[j + 2] = k4.z; kreg[j + 3] = k4.w;
        d0 += w[j]     * (q4.x - k4.x);
        d1 += w[j + 1] * (q4.y - k4.y);
        d2 += w[j + 2] * (q4.z - k4.z);
        d3 += w[j + 3] * (q4.w - k4.w);
      }
      float dv = (d0 + d1) + (d2 + d3);
      float c = betabuf[wave] * dv;
      #pragma unroll
      for (int j = 0; j < 64; j += 4) {
        w[j]     += c * kreg[j];
        w[j + 1] += c * kreg[j + 1];
        w[j + 2] += c * kreg[j + 2];
        w[j + 3] += c * kreg[j + 3];
      }
      if (wave == 0) {
        ys_bf[(size_t)(t * BSZ + b) * INDIM + head * DHEAD + lane] = f2bf(yout);
      }
      __syncthreads();  // beta barrier: q/k reads done before next overwrite
    }
  } else {
    // wave 3: wb, beta, x staging
    const float* wbrow = wb0 + (size_t)head * DHEAD * 4 + lane * 4;
    float4 wbv = *(const float4*)wbrow;
    float xv = xbase[lane];
    xbuf[lane] = xv;
    __syncthreads();  // prologue
    for (int t = 0; t < SLEN; ++t) {
      // beta = sigmoid(wb^T x)
      float p0 = wbv.x * xv, p1 = wbv.y * xv, p2 = wbv.z * xv, p3 = wbv.w * xv;
      #pragma unroll
      for (int s = 32; s >= 1; s >>= 1) {
        p0 += __shfl_xor(p0, s);
        p1 += __shfl_xor(p1, s);
        p2 += __shfl_xor(p2, s);
        p3 += __shfl_xor(p3, s);
      }
      float b0 = 1.f / (1.f + __expf(-p0));
      float b1 = 1.f / (1.f + __expf(-p1));
      float b2 = 1.f / (1.f + __expf(-p2));
      float b3 = 1.f / (1.f + __expf(-p3));
      if (lane == 0) {
        betabuf[0] = b0; betabuf[1] = b1; betabuf[2] = b2; betabuf[3] = b3;
      }
      float xnext = 0.f;
      if (t + 1 < SLEN) xnext = xbase[(size_t)(t + 1) * BSZ * INDIM + lane];
      __syncthreads();  // alpha
      // dvb = wb^T (q-k); wb += beta3 * k * dvb^T
      float qv = qbuf[lane];
      float kv = kbuf[lane];
      float qmk = qv - kv;
      float g0 = wbv.x * qmk, g1 = wbv.y * qmk, g2 = wbv.z * qmk, g3 = wbv.w * qmk;
      #pragma unroll
      for (int s = 32; s >= 1; s >>= 1) {
        g0 += __shfl_xor(g0, s);
        g1 += __shfl_xor(g1, s);
        g2 += __shfl_xor(g2, s);
        g3 += __shfl_xor(g3, s);
      }
      float cl = b3 * kv;
      wbv.x += cl * g0; wbv.y += cl * g1; wbv.z += cl * g2; wbv.w += cl * g3;
      xv = xnext;
      xbuf[lane] = xnext;   // stage x_{t+1} (readers finished xbuf at alpha)
      __syncthreads();  // beta barrier
    }
  }
}

// --------------------------------------------------------------------------
// Kernel 4: out = ys_bf16 @ out_w_bf16^T (MFMA) + LayerNorm(h) epilogue
// M=2048, N=1024, K=1024. 128x128 block tile, 2x2 waves of 64x64 each.
// --------------------------------------------------------------------------
__global__ __launch_bounds__(256, 1) void gemm_ln_k(
    const unsigned short* __restrict__ A,   // ys bf16 (2048 x 1024)
    const unsigned short* __restrict__ B,   // out_w bf16 (1024 x 1024), row n holds k-major
    const float* __restrict__ h,
    const float* __restrict__ stats,        // (2048 x 2): mu, rsig
    const float* __restrict__ gamma,
    const float* __restrict__ lbeta,
    float* __restrict__ out) {
  const int bx = blockIdx.x & 7;   // N tile (1024/128)
  const int by = blockIdx.x >> 3;  // M tile (2048/128)
  const int tid = threadIdx.x;
  const int wave = tid >> 6, lane = tid & 63;
  const int wr = wave >> 1, wc = wave & 1;
  const int rbase = by * 128 + wr * 64;
  const int nbase = bx * 128 + wc * 64;
  const int l16 = lane & 15;
  const int kofs = (lane >> 4) * 8;

  const short* Ap = (const short*)A;
  const short* Bp = (const short*)B;

  f32x4 acc[4][4];
  #pragma unroll
  for (int i = 0; i < 4; ++i)
    #pragma unroll
    for (int j = 0; j < 4; ++j)
      acc[i][j] = (f32x4){0.f, 0.f, 0.f, 0.f};

  for (int kk = 0; kk < INDIM; kk += 32) {
    bf16x8 af[4], bfv[4];
    #pragma unroll
    for (int i = 0; i < 4; ++i)
      af[i] = *(const bf16x8*)(Ap + (size_t)(rbase + i * 16 + l16) * INDIM + kk + kofs);
    #pragma unroll
    for (int j = 0; j < 4; ++j)
      bfv[j] = *(const bf16x8*)(Bp + (size_t)(nbase + j * 16 + l16) * INDIM + kk + kofs);
    #pragma unroll
    for (int i = 0; i < 4; ++i)
      #pragma unroll
      for (int j = 0; j < 4; ++j)
        acc[i][j] = __builtin_amdgcn_mfma_f32_16x16x32_bf16(af[i], bfv[j], acc[i][j], 0, 0, 0);
  }

  const int rq4 = (lane >> 4) * 4;
  #pragma unroll
  for (int i = 0; i < 4; ++i) {
    #pragma unroll
    for (int reg = 0; reg < 4; ++reg) {
      int r = rbase + i * 16 + rq4 + reg;
      float mu = stats[2 * r], rs = stats[2 * r + 1];
      #pragma unroll
      for (int j = 0; j < 4; ++j) {
        int n = nbase + j * 16 + l16;
        float hv = h[(size_t)r * INDIM + n];
        float hln = (hv - mu) * rs * gamma[n] + lbeta[n];
        out[(size_t)r * INDIM + n] = acc[i][j][reg] + hln;
      }
    }
  }
}

// --------------------------------------------------------------------------
extern "C" void kernel_launch(void* const* d_in, const int* in_sizes, int n_in,
                              void* d_out, int out_size, void* d_ws, size_t ws_size,
                              hipStream_t stream) {
  const float* h    = (const float*)d_in[0];
  const float* Wy   = (const float*)d_in[1];
  const float* Wq   = (const float*)d_in[2];
  const float* Wk   = (const float*)d_in[3];
  const float* wb   = (const float*)d_in[4];
  const float* outw = (const float*)d_in[5];
  const float* gam  = (const float*)d_in[6];
  const float* bet  = (const float*)d_in[7];
  float* out = (float*)d_out;

  char* ws = (char*)d_ws;
  unsigned short* ys_bf   = (unsigned short*)ws;                                  // 4 MB
  unsigned short* outw_bf = (unsigned short*)(ws + (size_t)2048 * 1024 * 2);      // 2 MB
  float* stats            = (float*)(ws + (size_t)2048 * 1024 * 2 + (size_t)1024 * 1024 * 2);

  conv_bf16_k<<<1024, 256, 0, stream>>>(outw, outw_bf);
  row_stats_k<<<2048, 256, 0, stream>>>(h, stats);
  srwm_scan_k<<<128, 256, 0, stream>>>(h, Wy, Wq, Wk, wb, ys_bf);
  gemm_ln_k<<<128, 256, 0, stream>>>(ys_bf, outw_bf, h, stats, gam, bet, out);
}

// Round 2
// 351.001 us; speedup vs baseline: 1.3025x; 1.3025x over previous
//
#include <hip/hip_runtime.h>
#include <hip/hip_bf16.h>

#define SLEN  256
#define BSZ   8
#define NHEAD 16
#define DHEAD 64
#define INDIM 1024
#define LN_EPS 1e-5f

typedef __attribute__((ext_vector_type(4))) float f32x4;
typedef __attribute__((ext_vector_type(8))) short bf16x8;

__device__ __forceinline__ int f_as_i(float f) { union { float f; int i; } u; u.f = f; return u.i; }
__device__ __forceinline__ float i_as_f(int i) { union { float f; int i; } u; u.i = i; return u.f; }

__device__ inline unsigned short f2bf(float x) {
  __hip_bfloat16 b = __float2bfloat16(x);
  union { __hip_bfloat16 b; unsigned short u; } cv;
  cv.b = b;
  return cv.u;
}

// DPP move, invalid lanes -> 0 (for sum)
template <int CTRL>
__device__ __forceinline__ float dpp0(float x) {
  return i_as_f(__builtin_amdgcn_update_dpp(0, f_as_i(x), CTRL, 0xF, 0xF, true));
}
// DPP move, invalid lanes -> self (for max)
template <int CTRL>
__device__ __forceinline__ float dppS(float x) {
  int xi = f_as_i(x);
  return i_as_f(__builtin_amdgcn_update_dpp(xi, xi, CTRL, 0xF, 0xF, false));
}

// Full 64-lane sum, result broadcast (via readlane 63 -> SGPR)
__device__ __forceinline__ float wave_sum64(float v) {
  v += dpp0<0x111>(v);  // row_shr:1
  v += dpp0<0x112>(v);  // row_shr:2
  v += dpp0<0x114>(v);  // row_shr:4
  v += dpp0<0x118>(v);  // row_shr:8
  v += dpp0<0x142>(v);  // row_bcast:15
  v += dpp0<0x143>(v);  // row_bcast:31
  return i_as_f(__builtin_amdgcn_readlane(f_as_i(v), 63));
}

__device__ __forceinline__ float wave_max64(float v) {
  v = fmaxf(v, dppS<0x111>(v));
  v = fmaxf(v, dppS<0x112>(v));
  v = fmaxf(v, dppS<0x114>(v));
  v = fmaxf(v, dppS<0x118>(v));
  v = fmaxf(v, dppS<0x142>(v));
  v = fmaxf(v, dppS<0x143>(v));
  return i_as_f(__builtin_amdgcn_readlane(f_as_i(v), 63));
}

// --------------------------------------------------------------------------
// Fused kernel: blocks 0..127 = SRWM scan (one chain each);
// blocks 128..1151 = out_w fp32->bf16; blocks 1152..3199 = LN row stats.
// --------------------------------------------------------------------------
__global__ __launch_bounds__(256, 1) void scan_prep_k(
    const float* __restrict__ h,
    const float* __restrict__ Wy0,
    const float* __restrict__ Wq0,
    const float* __restrict__ Wk0,
    const float* __restrict__ wb0,
    const float* __restrict__ outw,
    unsigned short* __restrict__ outw_bf,
    float* __restrict__ stats,
    unsigned short* __restrict__ ys_bf) {
  const int bid = blockIdx.x;
  const int tid = threadIdx.x;

  if (bid >= 128) {
    const int pb = bid - 128;
    if (pb < 1024) {
      // ---- convert out_w to bf16 ----
      int i = (pb * 256 + tid) * 4;
      float4 v = *(const float4*)(outw + i);
      ushort4 o;
      o.x = f2bf(v.x); o.y = f2bf(v.y); o.z = f2bf(v.z); o.w = f2bf(v.w);
      *(ushort4*)(outw_bf + i) = o;
    } else {
      // ---- LayerNorm row stats ----
      int r = pb - 1024;  // 0..2047
      const float* row = h + (size_t)r * INDIM;
      float4 v = *(const float4*)(row + tid * 4);
      float s  = v.x + v.y + v.z + v.w;
      float s2 = v.x * v.x + v.y * v.y + v.z * v.z + v.w * v.w;
      s  = wave_sum64(s);
      s2 = wave_sum64(s2);
      __shared__ float ls[4], ls2[4];
      int wv = tid >> 6;
      if ((tid & 63) == 0) { ls[wv] = s; ls2[wv] = s2; }
      __syncthreads();
      if (tid == 0) {
        float S  = ls[0] + ls[1] + ls[2] + ls[3];
        float S2 = ls2[0] + ls2[1] + ls2[2] + ls2[3];
        float mu = S * (1.0f / INDIM);
        float var = S2 * (1.0f / INDIM) - mu * mu;
        stats[2 * r]     = mu;
        stats[2 * r + 1] = rsqrtf(var + LN_EPS);
      }
    }
    return;
  }

  // ---------------- SRWM scan: one chain per block ----------------
  const int chain = bid;
  const int b    = chain >> 4;
  const int head = chain & 15;
  const int wv   = __builtin_amdgcn_readfirstlane(tid >> 6);  // uniform wave id
  const int lane = tid & 63;

  __shared__ __align__(16) float qbuf[2][64];
  __shared__ __align__(16) float kbuf[2][64];
  __shared__ __align__(16) float betabuf[2][4];

  const float* xrow0 = h + (size_t)b * INDIM + head * DHEAD;  // wave-uniform base

  if (wv < 3) {
    const float* Wsel = (wv == 0) ? Wy0 : ((wv == 1) ? Wq0 : Wk0);
    const float* wrow = Wsel + (size_t)head * DHEAD * DHEAD + (size_t)lane * DHEAD;
    float w[64];
    #pragma unroll
    for (int j = 0; j < 64; j += 4) {
      float4 t4 = *(const float4*)(wrow + j);
      w[j] = t4.x; w[j + 1] = t4.y; w[j + 2] = t4.z; w[j + 3] = t4.w;
    }
    // x_0 into (hopefully) SGPRs: wave-uniform loads
    float xs[64];
    #pragma unroll
    for (int j = 0; j < 64; ++j) xs[j] = xrow0[j];

    for (int t = 0; t < SLEN; ++t) {
      const int buf = t & 1;
      // ---- region B: v = W x_t (x in scalar regs, broadcast free) ----
      float a0 = 0.f, a1 = 0.f, a2 = 0.f, a3 = 0.f;
      #pragma unroll
      for (int j = 0; j < 64; j += 4) {
        a0 += w[j]     * xs[j];
        a1 += w[j + 1] * xs[j + 1];
        a2 += w[j + 2] * xs[j + 2];
        a3 += w[j + 3] * xs[j + 3];
      }
      float v = (a0 + a1) + (a2 + a3);

      // prefetch x_{t+1} into the same scalar regs (consumed next step;
      // latency hides under softmax + barrier + update)
      if (t + 1 < SLEN) {
        const float* xn = xrow0 + (size_t)(t + 1) * BSZ * INDIM;
        #pragma unroll
        for (int j = 0; j < 64; ++j) xs[j] = xn[j];
      }

      if (wv == 0) {
        ys_bf[(size_t)(t * BSZ + b) * INDIM + head * DHEAD + lane] = f2bf(v);
      } else {
        // wave-local softmax over 64 rows via DPP
        float m = wave_max64(v);
        float e = __expf(v - m);
        float ssum = wave_sum64(e);
        float sm = __fdividef(e, ssum);
        float* obuf = (wv == 1) ? qbuf[buf] : kbuf[buf];
        obuf[lane] = sm;
      }
      __syncthreads();  // publish q,k,beta (and x staging not needed)

      // ---- region C: dv = W (q-k); W += beta*dv*k^T ----
      float beta_c = betabuf[buf][wv];
      float kreg[64];
      float d0 = 0.f, d1 = 0.f, d2 = 0.f, d3 = 0.f;
      #pragma unroll
      for (int j = 0; j < 64; j += 4) {
        float4 q4 = *(const float4*)(&qbuf[buf][j]);
        float4 k4 = *(const float4*)(&kbuf[buf][j]);
        kreg[j] = k4.x; kreg[j + 1] = k4.y; kreg[j + 2] = k4.z; kreg[j + 3] = k4.w;
        d0 += w[j]     * (q4.x - k4.x);
        d1 += w[j + 1] * (q4.y - k4.y);
        d2 += w[j + 2] * (q4.z - k4.z);
        d3 += w[j + 3] * (q4.w - k4.w);
      }
      float dv = (d0 + d1) + (d2 + d3);
      float c = beta_c * dv;
      #pragma unroll
      for (int j = 0; j < 64; j += 4) {
        w[j]     += c * kreg[j];
        w[j + 1] += c * kreg[j + 1];
        w[j + 2] += c * kreg[j + 2];
        w[j + 3] += c * kreg[j + 3];
      }
      // no second barrier: buffers are double-buffered
    }
  } else {
    // wave 3: beta + wb update; per-lane x from global (double-buffered VGPR)
    const float* wbrow = wb0 + (size_t)head * DHEAD * 4 + lane * 4;
    float4 wbv = *(const float4*)wbrow;
    float xv = xrow0[lane];

    for (int t = 0; t < SLEN; ++t) {
      const int buf = t & 1;
      float xnext = 0.f;
      if (t + 1 < SLEN) xnext = xrow0[(size_t)(t + 1) * BSZ * INDIM + lane];

      float p0 = wave_sum64(wbv.x * xv);
      float p1 = wave_sum64(wbv.y * xv);
      float p2 = wave_sum64(wbv.z * xv);
      float p3 = wave_sum64(wbv.w * xv);
      float b0 = __fdividef(1.f, 1.f + __expf(-p0));
      float b1 = __fdividef(1.f, 1.f + __expf(-p1));
      float b2 = __fdividef(1.f, 1.f + __expf(-p2));
      float b3 = __fdividef(1.f, 1.f + __expf(-p3));
      if (lane == 0) {
        betabuf[buf][0] = b0; betabuf[buf][1] = b1;
        betabuf[buf][2] = b2; betabuf[buf][3] = b3;
      }
      __syncthreads();

      float qv = qbuf[buf][lane];
      float kv = kbuf[buf][lane];
      float qmk = qv - kv;
      float g0 = wave_sum64(wbv.x * qmk);
      float g1 = wave_sum64(wbv.y * qmk);
      float g2 = wave_sum64(wbv.z * qmk);
      float g3 = wave_sum64(wbv.w * qmk);
      float cl = b3 * kv;
      wbv.x += cl * g0; wbv.y += cl * g1; wbv.z += cl * g2; wbv.w += cl * g3;
      xv = xnext;
    }
  }
}

// --------------------------------------------------------------------------
// GEMM + LN epilogue: out = ys_bf16 @ out_w_bf16^T + LN(h)
// M=2048, N=1024, K=1024. 128x128 block tile, 2x2 waves of 64x64.
// --------------------------------------------------------------------------
__global__ __launch_bounds__(256, 1) void gemm_ln_k(
    const unsigned short* __restrict__ A,
    const unsigned short* __restrict__ B,
    const float* __restrict__ h,
    const float* __restrict__ stats,
    const float* __restrict__ gamma,
    const float* __restrict__ lbeta,
    float* __restrict__ out) {
  const int bx = blockIdx.x & 7;
  const int by = blockIdx.x >> 3;
  const int tid = threadIdx.x;
  const int wave = tid >> 6, lane = tid & 63;
  const int wr = wave >> 1, wc = wave & 1;
  const int rbase = by * 128 + wr * 64;
  const int nbase = bx * 128 + wc * 64;
  const int l16 = lane & 15;
  const int kofs = (lane >> 4) * 8;

  const short* Ap = (const short*)A;
  const short* Bp = (const short*)B;

  f32x4 acc[4][4];
  #pragma unroll
  for (int i = 0; i < 4; ++i)
    #pragma unroll
    for (int j = 0; j < 4; ++j)
      acc[i][j] = (f32x4){0.f, 0.f, 0.f, 0.f};

  for (int kk = 0; kk < INDIM; kk += 32) {
    bf16x8 af[4], bfv[4];
    #pragma unroll
    for (int i = 0; i < 4; ++i)
      af[i] = *(const bf16x8*)(Ap + (size_t)(rbase + i * 16 + l16) * INDIM + kk + kofs);
    #pragma unroll
    for (int j = 0; j < 4; ++j)
      bfv[j] = *(const bf16x8*)(Bp + (size_t)(nbase + j * 16 + l16) * INDIM + kk + kofs);
    #pragma unroll
    for (int i = 0; i < 4; ++i)
      #pragma unroll
      for (int j = 0; j < 4; ++j)
        acc[i][j] = __builtin_amdgcn_mfma_f32_16x16x32_bf16(af[i], bfv[j], acc[i][j], 0, 0, 0);
  }

  const int rq4 = (lane >> 4) * 4;
  #pragma unroll
  for (int i = 0; i < 4; ++i) {
    #pragma unroll
    for (int reg = 0; reg < 4; ++reg) {
      int r = rbase + i * 16 + rq4 + reg;
      float mu = stats[2 * r], rs = stats[2 * r + 1];
      #pragma unroll
      for (int j = 0; j < 4; ++j) {
        int n = nbase + j * 16 + l16;
        float hv = h[(size_t)r * INDIM + n];
        float hln = (hv - mu) * rs * gamma[n] + lbeta[n];
        out[(size_t)r * INDIM + n] = acc[i][j][reg] + hln;
      }
    }
  }
}

// --------------------------------------------------------------------------
extern "C" void kernel_launch(void* const* d_in, const int* in_sizes, int n_in,
                              void* d_out, int out_size, void* d_ws, size_t ws_size,
                              hipStream_t stream) {
  const float* h    = (const float*)d_in[0];
  const float* Wy   = (const float*)d_in[1];
  const float* Wq   = (const float*)d_in[2];
  const float* Wk   = (const float*)d_in[3];
  const float* wb   = (const float*)d_in[4];
  const float* outw = (const float*)d_in[5];
  const float* gam  = (const float*)d_in[6];
  const float* bet  = (const float*)d_in[7];
  float* out = (float*)d_out;

  char* ws = (char*)d_ws;
  unsigned short* ys_bf   = (unsigned short*)ws;                                  // 4 MB
  unsigned short* outw_bf = (unsigned short*)(ws + (size_t)2048 * 1024 * 2);      // 2 MB
  float* stats            = (float*)(ws + (size_t)2048 * 1024 * 2 + (size_t)1024 * 1024 * 2);

  scan_prep_k<<<128 + 1024 + 2048, 256, 0, stream>>>(h, Wy, Wq, Wk, wb, outw,
                                                     outw_bf, stats, ys_bf);
  gemm_ln_k<<<128, 256, 0, stream>>>(ys_bf, outw_bf, h, stats, gam, bet, out);
}